// Round 2
// baseline (466.621 us; speedup 1.0000x reference)
//
#include <hip/hip_runtime.h>

#define B_ 4
#define H_ 8
#define LQ_ 256
#define LK_ 256
#define DK_ 64
#define BH_ (B_*H_)           // 32
#define NROWS (BH_*LQ_)       // 8192 rows per projection
#define QT 8                  // q rows per block in score kernel

// ---------------- K1: projections qp = q*Wq^T + bq, kp = k*Wk^T + bk ----
// grid 512: blocks [0,256) -> q-proj, [256,512) -> k-proj; 32 rows/block.
__global__ __launch_bounds__(256) void proj_kernel(
    const float* __restrict__ qin, const float* __restrict__ kin,
    const float* __restrict__ Wq, const float* __restrict__ bq,
    const float* __restrict__ Wk, const float* __restrict__ bk,
    float* __restrict__ qp, float* __restrict__ kp)
{
    const int which = blockIdx.x >> 8;           // 0 = q, 1 = k
    const int rb    = (blockIdx.x & 255) * 32;   // first row of this block
    const float* in   = which ? kin : qin;
    const float* W    = which ? Wk  : Wq;
    const float* bias = which ? bk  : bq;
    float* out        = which ? kp  : qp;

    __shared__ float in_s[32*68];                // pad 68 -> conflict-free
    const int tid = threadIdx.x;

    // stage 32x64 input rows, coalesced float4
    {
        const float4* g = (const float4*)(in + rb*64);
        #pragma unroll
        for (int p = 0; p < 2; ++p) {
            int f = tid + p*256;                 // float4 index, 512 total
            float4 x = g[f];
            int row = f >> 4;
            int col = (f & 15) * 4;
            *(float4*)&in_s[row*68 + col] = x;
        }
    }
    __syncthreads();

    const int r  = tid >> 3;                     // 0..31 row
    const int gg = tid & 7;                      // e-group: e = gg*8 + i
    float acc[8];
    #pragma unroll
    for (int i = 0; i < 8; ++i) acc[i] = 0.f;

    const float4* W4 = (const float4*)W;         // W[e][d], row-major
    #pragma unroll
    for (int i = 0; i < 8; ++i) {
        const int e = gg*8 + i;
        #pragma unroll
        for (int j = 0; j < 16; ++j) {
            float4 w = W4[e*16 + j];             // L1-resident (16 KB)
            float4 x = *(const float4*)&in_s[r*68 + j*4];
            acc[i] = fmaf(w.x, x.x, acc[i]);
            acc[i] = fmaf(w.y, x.y, acc[i]);
            acc[i] = fmaf(w.z, x.z, acc[i]);
            acc[i] = fmaf(w.w, x.w, acc[i]);
        }
    }
    float* orow = out + (rb + r)*64 + gg*8;
    float4 o0, o1;
    o0.x = acc[0] + bias[gg*8+0]; o0.y = acc[1] + bias[gg*8+1];
    o0.z = acc[2] + bias[gg*8+2]; o0.w = acc[3] + bias[gg*8+3];
    o1.x = acc[4] + bias[gg*8+4]; o1.y = acc[5] + bias[gg*8+5];
    o1.z = acc[6] + bias[gg*8+6]; o1.w = acc[7] + bias[gg*8+7];
    *(float4*)&orow[0] = o0;
    *(float4*)&orow[4] = o1;
}

// ---------------- K2: scores + softmax -> attn ----------------
// grid = BH_ * (LQ_/QT) = 1024 blocks, 256 threads. Thread t owns k = t.
// score = vs_b + sum(vs) - 2 * sum_d vs[d] * rcp(exp2(C2*qp_d + C2*kp_d) + 1)
// qp (LDS) and kp (regs) are PRE-SCALED by C2 = 2*log2(e).
// d-loop split into two 32-wide halves: only 8 float4 of kp live at a time
// -> fits 128 VGPRs at 4 waves/SIMD (R1 post-mortem: 256 VGPR + 82 MB spill
//    traffic was the 89-us pathology).
__global__ __launch_bounds__(256, 4) void score_softmax_kernel(
    const float* __restrict__ qp, const float* __restrict__ kp,
    const float* __restrict__ vs_w, const float* __restrict__ vs_b,
    float* __restrict__ attn)
{
    const int bh = blockIdx.x >> 5;
    const int qt = blockIdx.x & 31;
    const int t  = threadIdx.x;
    const int lane = t & 63, wid = t >> 6;

    const float C2 = 2.8853900817779268f;   // 2*log2(e)

    __shared__ float qp_s[QT*64];           // pre-scaled by C2
    __shared__ float vs_s[64];
    __shared__ float redm[QT][4];
    __shared__ float reds[QT][4];

    {
        const float4* g = (const float4*)(qp + (bh*LQ_ + qt*QT)*64);
        if (t < QT*16) {
            float4 x = g[t];
            x.x *= C2; x.y *= C2; x.z *= C2; x.w *= C2;
            ((float4*)qp_s)[t] = x;
        }
        if (t >= 128 && t < 192) vs_s[t-128] = vs_w[t-128];
    }
    __syncthreads();

    // base = vs_b + sum(vs)   (LDS broadcast reads, once per block)
    float S = vs_b[0];
    #pragma unroll
    for (int j = 0; j < 16; ++j) {
        float4 w = *(const float4*)&vs_s[j*4];
        S += (w.x + w.y) + (w.z + w.w);
    }

    const float4* kg = (const float4*)(kp + (bh*LK_ + t)*64);

    float sc[QT];
    #pragma unroll
    for (int q = 0; q < QT; ++q) sc[q] = 0.f;

    #pragma unroll
    for (int half = 0; half < 2; ++half) {
        float4 kr[8];                        // 32 VGPRs live
        #pragma unroll
        for (int j = 0; j < 8; ++j) {
            float4 kv = kg[half*8 + j];
            kr[j].x = kv.x*C2; kr[j].y = kv.y*C2;
            kr[j].z = kv.z*C2; kr[j].w = kv.w*C2;
        }
        #pragma unroll
        for (int q = 0; q < QT; ++q) {
            float a0 = 0.f, a1 = 0.f;        // 2 chains (TLP > ILP here)
            #pragma unroll
            for (int j = 0; j < 8; ++j) {
                float4 qv = *(const float4*)&qp_s[q*64 + half*32 + j*4];
                float4 wv = *(const float4*)&vs_s[half*32 + j*4];
                float4 kv = kr[j];
                a0 = fmaf(wv.x, __builtin_amdgcn_rcpf(__builtin_amdgcn_exp2f(qv.x+kv.x)+1.f), a0);
                a1 = fmaf(wv.y, __builtin_amdgcn_rcpf(__builtin_amdgcn_exp2f(qv.y+kv.y)+1.f), a1);
                a0 = fmaf(wv.z, __builtin_amdgcn_rcpf(__builtin_amdgcn_exp2f(qv.z+kv.z)+1.f), a0);
                a1 = fmaf(wv.w, __builtin_amdgcn_rcpf(__builtin_amdgcn_exp2f(qv.w+kv.w)+1.f), a1);
            }
            sc[q] += a0 + a1;
        }
    }
    #pragma unroll
    for (int q = 0; q < QT; ++q) sc[q] = S - 2.f*sc[q];

    // softmax across the 256 threads (k axis), batched over the QT rows
    #pragma unroll
    for (int q = 0; q < QT; ++q) {
        float m = sc[q];
        #pragma unroll
        for (int off = 32; off; off >>= 1) m = fmaxf(m, __shfl_xor(m, off, 64));
        if (lane == 0) redm[q][wid] = m;
    }
    __syncthreads();
    const float L2E = 1.4426950408889634f;
    float p[QT];
    #pragma unroll
    for (int q = 0; q < QT; ++q) {
        float m = fmaxf(fmaxf(redm[q][0], redm[q][1]), fmaxf(redm[q][2], redm[q][3]));
        float pp = __builtin_amdgcn_exp2f((sc[q] - m) * L2E);
        p[q] = pp;
        float s = pp;
        #pragma unroll
        for (int off = 32; off; off >>= 1) s += __shfl_xor(s, off, 64);
        if (lane == 0) reds[q][wid] = s;
    }
    __syncthreads();
    #pragma unroll
    for (int q = 0; q < QT; ++q) {
        float s = (reds[q][0] + reds[q][1]) + (reds[q][2] + reds[q][3]);
        float a = p[q] * __builtin_amdgcn_rcpf(s);
        attn[(bh*LQ_ + qt*QT + q)*LK_ + t] = a;   // coalesced
    }
}

// ---------------- K3: out = attn @ v ----------------
// grid = BH_ * (LQ_/16) = 512 blocks, 256 threads; 16 q-rows x 64 d per block.
__global__ __launch_bounds__(256) void pv_kernel(
    const float* __restrict__ attn, const float* __restrict__ v,
    float* __restrict__ out)
{
    const int bh = blockIdx.x >> 4;
    const int q0 = (blockIdx.x & 15) * 16;
    const int t  = threadIdx.x;
    const int dg = t & 15;        // d = dg*4 .. +3
    const int rg = t >> 4;        // row 0..15

    __shared__ float at_s[16*68];     // pad 68: aligned float4, tolerable conflicts
    __shared__ float v_s[64*64];

    float4 acc = {0.f, 0.f, 0.f, 0.f};
    for (int c = 0; c < 4; ++c) {
        // stage attn 16x64 chunk (1 float4/thread, coalesced)
        {
            int row = t >> 4, k0 = (t & 15) * 4;
            float4 a4 = *(const float4*)&attn[(bh*LQ_ + q0 + row)*LK_ + c*64 + k0];
            *(float4*)&at_s[row*68 + k0] = a4;
        }
        // stage v 64x64 chunk (4 float4/thread, coalesced)
        #pragma unroll
        for (int p = 0; p < 4; ++p) {
            int f = t + p*256;
            int kk = f >> 4, col = (f & 15) * 4;
            *(float4*)&v_s[kk*64 + col] =
                *(const float4*)&v[(bh*LK_ + c*64 + kk)*DK_ + col];
        }
        __syncthreads();
        #pragma unroll
        for (int kkg = 0; kkg < 16; ++kkg) {
            float av[4];
            *(float4*)av = *(const float4*)&at_s[rg*68 + kkg*4];  // broadcast
            #pragma unroll
            for (int u = 0; u < 4; ++u) {
                float4 vv = *(const float4*)&v_s[(kkg*4+u)*64 + dg*4]; // 2-way: free
                acc.x = fmaf(av[u], vv.x, acc.x);
                acc.y = fmaf(av[u], vv.y, acc.y);
                acc.z = fmaf(av[u], vv.z, acc.z);
                acc.w = fmaf(av[u], vv.w, acc.w);
            }
        }
        __syncthreads();
    }
    *(float4*)&out[(bh*LQ_ + q0 + rg)*DK_ + dg*4] = acc;
}

extern "C" void kernel_launch(void* const* d_in, const int* in_sizes, int n_in,
                              void* d_out, int out_size, void* d_ws, size_t ws_size,
                              hipStream_t stream) {
    const float* q    = (const float*)d_in[0];
    const float* k    = (const float*)d_in[1];
    const float* v    = (const float*)d_in[2];
    const float* Wq_w = (const float*)d_in[3];
    const float* Wq_b = (const float*)d_in[4];
    const float* Wk_w = (const float*)d_in[5];
    const float* Wk_b = (const float*)d_in[6];
    const float* vs_w = (const float*)d_in[7];
    const float* vs_b = (const float*)d_in[8];

    float* out  = (float*)d_out;                      // [B,H,LQ,DK]
    float* attn = out + B_*H_*LQ_*DK_;                // [B,H,LQ,LK]
    float* qp   = (float*)d_ws;                       // 2 MB
    float* kp   = qp + NROWS*64;                      // 2 MB

    proj_kernel<<<512, 256, 0, stream>>>(q, k, Wq_w, Wq_b, Wk_w, Wk_b, qp, kp);
    score_softmax_kernel<<<BH_*(LQ_/QT), 256, 0, stream>>>(qp, kp, vs_w, vs_b, attn);
    pv_kernel<<<BH_*(LQ_/16), 256, 0, stream>>>(attn, v, out);
}

// Round 3
// 122.432 us; speedup vs baseline: 3.8113x; 3.8113x over previous
//
#include <hip/hip_runtime.h>

#define B_ 4
#define H_ 8
#define LQ_ 256
#define LK_ 256
#define DK_ 64
#define BH_ (B_*H_)           // 32
#define NROWS (BH_*LQ_)       // 8192 rows per projection
#define QT 4                  // q rows per block in score kernel

// ---------------- K1: projections qp = q*Wq^T + bq, kp = k*Wk^T + bk ----
// grid 512: blocks [0,256) -> q-proj, [256,512) -> k-proj; 32 rows/block.
// W staged in LDS at stride 68; thread's e = gg + i*8 so the 8 lane-groups
// read banks {4g..4g+3} -> conflict-free (the old e=gg*8+i pattern was an
// 8-way replay on global/L1).
__global__ __launch_bounds__(256) void proj_kernel(
    const float* __restrict__ qin, const float* __restrict__ kin,
    const float* __restrict__ Wq, const float* __restrict__ bq,
    const float* __restrict__ Wk, const float* __restrict__ bk,
    float* __restrict__ qp, float* __restrict__ kp)
{
    const int which = blockIdx.x >> 8;           // 0 = q, 1 = k
    const int rb    = (blockIdx.x & 255) * 32;   // first row of this block
    const float* in   = which ? kin : qin;
    const float* W    = which ? Wk  : Wq;
    const float* bias = which ? bk  : bq;
    float* out        = which ? kp  : qp;

    __shared__ float in_s[32*68];
    __shared__ float w_s[64*68];
    const int tid = threadIdx.x;

    // stage 32x64 input rows, coalesced float4
    {
        const float4* g = (const float4*)(in + rb*64);
        #pragma unroll
        for (int p = 0; p < 2; ++p) {
            int f = tid + p*256;
            float4 x = g[f];
            *(float4*)&in_s[(f>>4)*68 + (f&15)*4] = x;
        }
    }
    // stage W 64x64, coalesced float4, stride 68
    {
        const float4* g = (const float4*)W;
        #pragma unroll
        for (int p = 0; p < 4; ++p) {
            int f = tid + p*256;
            float4 x = g[f];
            *(float4*)&w_s[(f>>4)*68 + (f&15)*4] = x;
        }
    }
    __syncthreads();

    const int r  = tid >> 3;                     // 0..31 row
    const int gg = tid & 7;                      // e = gg + i*8
    float acc[8];
    #pragma unroll
    for (int i = 0; i < 8; ++i) acc[i] = 0.f;

    #pragma unroll
    for (int j = 0; j < 16; ++j) {
        float4 x = *(const float4*)&in_s[r*68 + j*4];   // 8-lane broadcast, cf-free
        #pragma unroll
        for (int i = 0; i < 8; ++i) {
            const int e = gg + i*8;
            float4 w = *(const float4*)&w_s[e*68 + j*4]; // banks 4g..4g+3, cf-free
            acc[i] = fmaf(w.x, x.x, acc[i]);
            acc[i] = fmaf(w.y, x.y, acc[i]);
            acc[i] = fmaf(w.z, x.z, acc[i]);
            acc[i] = fmaf(w.w, x.w, acc[i]);
        }
    }
    float* orow = out + (rb + r)*64;
    #pragma unroll
    for (int i = 0; i < 8; ++i) {
        const int e = gg + i*8;
        orow[e] = acc[i] + bias[e];   // 8 rows x 8-consecutive per wave: 32B segments
    }
}

// ---------------- K2: scores + softmax -> attn ----------------
// grid = BH_ * (LQ_/QT) = 2048 blocks, 256 threads. Thread t owns k = t.
// score = vs_b + sum(vs) - 2 * sum_d vs[d] * rcp(exp2(C2*qp_d + C2*kp_d) + 1)
// qp (LDS) and kp (regs) pre-scaled by C2 = 2*log2(e).
// kp processed in QUARTERS (kr[4] = 16 VGPRs live), #pragma unroll 1 so the
// compiler cannot hoist all 16 loads (R1: 256 VGPR; R2: forced 64 VGPR ->
// 1.1 GB scratch spill. Natural small live set, no min-waves forcing.)
// No max-subtraction: |score| <= |vs_b| + sum|vs| <= 8.2 -> exp safe in fp32.
__global__ __launch_bounds__(256) void score_softmax_kernel(
    const float* __restrict__ qp, const float* __restrict__ kp,
    const float* __restrict__ vs_w, const float* __restrict__ vs_b,
    float* __restrict__ attn)
{
    const int bh = blockIdx.x >> 6;
    const int qt = blockIdx.x & 63;
    const int t  = threadIdx.x;
    const int lane = t & 63, wid = t >> 6;

    const float C2  = 2.8853900817779268f;   // 2*log2(e)
    const float L2E = 1.4426950408889634f;

    __shared__ float qp_s[QT*64];            // pre-scaled by C2
    __shared__ float vs_s[64];
    __shared__ float reds[QT][4];

    if (t < QT*16) {
        float4 x = ((const float4*)(qp + (bh*LQ_ + qt*QT)*64))[t];
        x.x *= C2; x.y *= C2; x.z *= C2; x.w *= C2;
        ((float4*)qp_s)[t] = x;
    } else if (t < QT*16 + 64) {
        vs_s[t - QT*16] = vs_w[t - QT*16];
    }
    __syncthreads();

    // base = vs_b + sum(vs)   (LDS broadcast reads)
    float S = vs_b[0];
    #pragma unroll
    for (int j = 0; j < 16; ++j) {
        float4 w = *(const float4*)&vs_s[j*4];
        S += (w.x + w.y) + (w.z + w.w);
    }

    const float4* kg = (const float4*)(kp + (bh*LK_ + t)*64);

    float sc[QT] = {0.f, 0.f, 0.f, 0.f};
    #pragma unroll 1
    for (int quar = 0; quar < 4; ++quar) {
        float4 kr[4];                        // 16 VGPRs live
        #pragma unroll
        for (int j = 0; j < 4; ++j) {
            float4 kv = kg[quar*4 + j];
            kr[j].x = kv.x*C2; kr[j].y = kv.y*C2;
            kr[j].z = kv.z*C2; kr[j].w = kv.w*C2;
        }
        #pragma unroll
        for (int q = 0; q < QT; ++q) {
            float a0 = 0.f, a1 = 0.f;
            #pragma unroll
            for (int j = 0; j < 4; ++j) {
                float4 qv = *(const float4*)&qp_s[q*64 + quar*16 + j*4]; // broadcast
                float4 wv = *(const float4*)&vs_s[quar*16 + j*4];        // broadcast
                float4 kv = kr[j];
                a0 = fmaf(wv.x, __builtin_amdgcn_rcpf(__builtin_amdgcn_exp2f(qv.x+kv.x)+1.f), a0);
                a1 = fmaf(wv.y, __builtin_amdgcn_rcpf(__builtin_amdgcn_exp2f(qv.y+kv.y)+1.f), a1);
                a0 = fmaf(wv.z, __builtin_amdgcn_rcpf(__builtin_amdgcn_exp2f(qv.z+kv.z)+1.f), a0);
                a1 = fmaf(wv.w, __builtin_amdgcn_rcpf(__builtin_amdgcn_exp2f(qv.w+kv.w)+1.f), a1);
            }
            sc[q] += a0 + a1;
        }
    }

    // p = exp(score), softmax over k (no max subtraction; scores bounded)
    float p[QT];
    #pragma unroll
    for (int q = 0; q < QT; ++q) {
        p[q] = __builtin_amdgcn_exp2f((S - 2.f*sc[q]) * L2E);
        float s = p[q];
        #pragma unroll
        for (int off = 32; off; off >>= 1) s += __shfl_xor(s, off, 64);
        if (lane == 0) reds[q][wid] = s;
    }
    __syncthreads();
    #pragma unroll
    for (int q = 0; q < QT; ++q) {
        float s = (reds[q][0] + reds[q][1]) + (reds[q][2] + reds[q][3]);
        float a = p[q] * __builtin_amdgcn_rcpf(s);
        attn[(bh*LQ_ + qt*QT + q)*LK_ + t] = a;   // coalesced
    }
}

// ---------------- K3: out = attn @ v ----------------
// grid = BH_ * (LQ_/16) = 512 blocks, 256 threads; 16 q-rows x 64 d per block.
__global__ __launch_bounds__(256) void pv_kernel(
    const float* __restrict__ attn, const float* __restrict__ v,
    float* __restrict__ out)
{
    const int bh = blockIdx.x >> 4;
    const int q0 = (blockIdx.x & 15) * 16;
    const int t  = threadIdx.x;
    const int dg = t & 15;        // d = dg*4 .. +3
    const int rg = t >> 4;        // row 0..15

    __shared__ float at_s[16*68];
    __shared__ float v_s[64*64];

    float4 acc = {0.f, 0.f, 0.f, 0.f};
    for (int c = 0; c < 4; ++c) {
        {
            int row = t >> 4, k0 = (t & 15) * 4;
            float4 a4 = *(const float4*)&attn[(bh*LQ_ + q0 + row)*LK_ + c*64 + k0];
            *(float4*)&at_s[row*68 + k0] = a4;
        }
        #pragma unroll
        for (int p = 0; p < 4; ++p) {
            int f = t + p*256;
            int kk = f >> 4, col = (f & 15) * 4;
            *(float4*)&v_s[kk*64 + col] =
                *(const float4*)&v[(bh*LK_ + c*64 + kk)*DK_ + col];
        }
        __syncthreads();
        #pragma unroll
        for (int kkg = 0; kkg < 16; ++kkg) {
            float av[4];
            *(float4*)av = *(const float4*)&at_s[rg*68 + kkg*4];  // broadcast
            #pragma unroll
            for (int u = 0; u < 4; ++u) {
                float4 vv = *(const float4*)&v_s[(kkg*4+u)*64 + dg*4]; // 2-way: free
                acc.x = fmaf(av[u], vv.x, acc.x);
                acc.y = fmaf(av[u], vv.y, acc.y);
                acc.z = fmaf(av[u], vv.z, acc.z);
                acc.w = fmaf(av[u], vv.w, acc.w);
            }
        }
        __syncthreads();
    }
    *(float4*)&out[(bh*LQ_ + q0 + rg)*DK_ + dg*4] = acc;
}

extern "C" void kernel_launch(void* const* d_in, const int* in_sizes, int n_in,
                              void* d_out, int out_size, void* d_ws, size_t ws_size,
                              hipStream_t stream) {
    const float* q    = (const float*)d_in[0];
    const float* k    = (const float*)d_in[1];
    const float* v    = (const float*)d_in[2];
    const float* Wq_w = (const float*)d_in[3];
    const float* Wq_b = (const float*)d_in[4];
    const float* Wk_w = (const float*)d_in[5];
    const float* Wk_b = (const float*)d_in[6];
    const float* vs_w = (const float*)d_in[7];
    const float* vs_b = (const float*)d_in[8];

    float* out  = (float*)d_out;                      // [B,H,LQ,DK]
    float* attn = out + B_*H_*LQ_*DK_;                // [B,H,LQ,LK]
    float* qp   = (float*)d_ws;                       // 2 MB
    float* kp   = qp + NROWS*64;                      // 2 MB

    proj_kernel<<<512, 256, 0, stream>>>(q, k, Wq_w, Wq_b, Wk_w, Wk_b, qp, kp);
    score_softmax_kernel<<<BH_*(LQ_/QT), 256, 0, stream>>>(qp, kp, vs_w, vs_b, attn);
    pv_kernel<<<BH_*(LQ_/16), 256, 0, stream>>>(attn, v, out);
}